// Round 4
// baseline (21.345 us; speedup 1.0000x reference)
//
#include <hip/hip_runtime.h>

// MedSAM3D neighborhood compression: out[f,h,w] = sum_n img[f,h,w,n]*W[f,n]
// B=1, F=256, H=W=64, N=25, fp32. 105 MB read + 4.2 MB write, memory-bound.
//
// R4: persistent waves + 2-deep double-buffered LDS + COUNTED vmcnt (T3/T4).
// R1/R3 both hit 5.1 TB/s: every wave drained vmcnt to 0 each chunk, so its
// in-flight loads collapsed to zero once per chunk. Here each wave processes
// ~5-6 chunks, staging chunk i+1 (7 global_load_lds) BEFORE waiting on chunk
// i with vmcnt(7) -- loads stay in flight across compute phases.
//
// vmcnt(7) derivation (stores also count in vmcnt on gfx9):
//   prologue: stage(c0)                        -> outstanding S0=7
//   iter0: stage(c1)=14; vmcnt(7) retires S0; compute; store0 -> S1+st0=8
//   iterK: stage(c_k+1)=15; vmcnt(7) retires S_k(7)+st_{k-1}(1) -> exact.
//   final iter: no stage; outstanding=8; vmcnt(0) drains all.

constexpr int NN    = 25;
constexpr int BLOCK = 256;
constexpr int WAVES = 4;
constexpr int OPW   = 64;           // outputs (=lanes) per chunk
constexpr int FPW   = OPW * NN;     // 1600 floats per chunk
constexpr int GRID  = 768;          // 3 blocks/CU exactly (51.2 KB LDS each)

typedef __attribute__((address_space(3))) void       lds_void;
typedef const __attribute__((address_space(1))) void gbl_void;

__device__ __forceinline__ void stage_chunk(float* lds_dst, const float* gsrc,
                                            int lane) {
    // 1600 floats: 6 x (64 lanes x 16B) + 1 x (64 lanes x 4B), linear dest.
    #pragma unroll
    for (int k = 0; k < 6; ++k)
        __builtin_amdgcn_global_load_lds(
            (gbl_void*)(gsrc + k * 256 + lane * 4),
            (lds_void*)(lds_dst + k * 256), 16, 0, 0);
    __builtin_amdgcn_global_load_lds(
        (gbl_void*)(gsrc + 1536 + lane),
        (lds_void*)(lds_dst + 1536), 4, 0, 0);
}

__global__ __launch_bounds__(BLOCK) void medsam_compress_kernel(
    const float* __restrict__ img,   // [F*H*W*N]
    const float* __restrict__ W,     // [F*N]
    float* __restrict__ out,         // [F*H*W]
    int nchunk)                      // 16384
{
    __shared__ float lds[WAVES][2][FPW];   // 4 x 2 x 6400 B = 51,200 B

    const int tid  = threadIdx.x;
    const int w    = tid >> 6;
    const int lane = tid & 63;
    const int gw0  = __builtin_amdgcn_readfirstlane(blockIdx.x * WAVES + w);
    const int step = GRID * WAVES;         // 3072 waves total

    int c   = gw0;
    int cur = 0;

    if (c < nchunk)
        stage_chunk(&lds[w][0][0], img + (long long)c * FPW, lane);

    while (c < nchunk) {
        const int nxt = c + step;
        if (nxt < nchunk) {
            stage_chunk(&lds[w][cur ^ 1][0], img + (long long)nxt * FPW, lane);
            asm volatile("s_waitcnt vmcnt(7)" ::: "memory");
        } else {
            asm volatile("s_waitcnt vmcnt(0)" ::: "memory");
        }
        __builtin_amdgcn_sched_barrier(0);

        // weights: channel f = c/64 is wave-uniform (c is SGPR-derived)
        const int f = c >> 6;
        const float* __restrict__ Wf = W + f * NN;
        float wreg[NN];
        #pragma unroll
        for (int n = 0; n < NN; ++n) wreg[n] = Wf[n];

        // dot: 25 ds_read_b32, lane stride 25 (odd) -> 2 lanes/bank, free
        const float* row = &lds[w][cur][lane * NN];
        float acc = 0.f;
        #pragma unroll
        for (int n = 0; n < NN; ++n)
            acc += row[n] * wreg[n];

        out[(long long)c * OPW + lane] = acc;

        cur ^= 1;
        c = nxt;
    }
}

extern "C" void kernel_launch(void* const* d_in, const int* in_sizes, int n_in,
                              void* d_out, int out_size, void* d_ws, size_t ws_size,
                              hipStream_t stream) {
    const float* img = (const float*)d_in[0];  // (1,256,64,64,25) f32
    const float* W   = (const float*)d_in[1];  // (256,25) f32
    float* out       = (float*)d_out;          // (1,256,64,64) f32

    const int nchunk = out_size / OPW;         // 16384
    medsam_compress_kernel<<<GRID, BLOCK, 0, stream>>>(img, W, out, nchunk);
}

// Round 5
// 20.562 us; speedup vs baseline: 1.0381x; 1.0381x over previous
//
#include <hip/hip_runtime.h>

// MedSAM3D neighborhood compression: out[f,h,w] = sum_n img[f,h,w,n]*W[f,n]
// B=1, F=256, H=W=64, N=25, fp32. 105 MB read + 4.2 MB write.
//
// R5: single-variable probe vs R3 -- identical structure, but staging loads
// carry the NT (non-temporal) cache-policy bit (aux=2). R1/R3/R4 (three
// disjoint structures) all converged at 5.12 TB/s; every per-CU pipe has
// headroom. This tests the last orthogonal axis: L1/L2 allocation overhead
// on a zero-reuse read stream. Unchanged => read-fabric ceiling => ROOFLINE.

constexpr int NN    = 25;
constexpr int BLOCK = 256;
constexpr int WAVES = BLOCK / 64;
constexpr int OPW   = 64;          // outputs per wave
constexpr int FPW   = OPW * NN;    // 1600 floats per wave

typedef __attribute__((address_space(3))) void       lds_void;
typedef const __attribute__((address_space(1))) void gbl_void;

__global__ __launch_bounds__(BLOCK) void medsam_compress_kernel(
    const float* __restrict__ img,   // [F*H*W*N]
    const float* __restrict__ W,     // [F*N]
    float* __restrict__ out)         // [F*H*W]
{
    __shared__ float lds[WAVES][FPW];   // 4 x 6400 B = 25,600 B

    const int tid  = threadIdx.x;
    const int w    = tid >> 6;          // wave id in block (uniform)
    const int lane = tid & 63;
    const int gw   = blockIdx.x * WAVES + w;   // global wave id

    const float* gbase = img + (long long)gw * FPW;

    // ---- stage 1600 floats: 6 x (64 lanes x 16B) + 1 x (64 lanes x 4B) ----
    // aux=2 -> NT bit (gfx940+ CPol: SC0=1, NT=2, SC1=16): non-temporal,
    // skip L1 allocation on a stream with zero reuse.
    #pragma unroll
    for (int k = 0; k < 6; ++k) {
        __builtin_amdgcn_global_load_lds(
            (gbl_void*)(gbase + k * 256 + lane * 4),   // per-lane global src
            (lds_void*)&lds[w][k * 256],               // wave-uniform LDS base
            16, 0, 2);
    }
    __builtin_amdgcn_global_load_lds(
        (gbl_void*)(gbase + 1536 + lane),
        (lds_void*)&lds[w][1536],
        4, 0, 2);

    // ---- weights: channel f = gw/64 (wave-uniform) -> scalar loads ----
    const int f = __builtin_amdgcn_readfirstlane(gw >> 6);
    const float* __restrict__ Wf = W + f * NN;
    float wreg[NN];
    #pragma unroll
    for (int n = 0; n < NN; ++n) wreg[n] = Wf[n];

    // ---- wave-scope wait: our 7 staging loads are the only vmcnt ops ----
    asm volatile("s_waitcnt vmcnt(0)" ::: "memory");
    __builtin_amdgcn_sched_barrier(0);

    // ---- dot: 25 ds_read_b32, lane stride 25 (odd) -> conflict-free ----
    const float* row = &lds[w][lane * NN];
    float acc = 0.f;
    #pragma unroll
    for (int n = 0; n < NN; ++n)
        acc += row[n] * wreg[n];

    out[(long long)gw * OPW + lane] = acc;
}

extern "C" void kernel_launch(void* const* d_in, const int* in_sizes, int n_in,
                              void* d_out, int out_size, void* d_ws, size_t ws_size,
                              hipStream_t stream) {
    const float* img = (const float*)d_in[0];  // (1,256,64,64,25) f32
    const float* W   = (const float*)d_in[1];  // (256,25) f32
    float* out       = (float*)d_out;          // (1,256,64,64) f32

    const int grid = out_size / (OPW * WAVES); // 4096
    medsam_compress_kernel<<<grid, BLOCK, 0, stream>>>(img, W, out);
}

// Round 6
// 19.554 us; speedup vs baseline: 1.0916x; 1.0515x over previous
//
#include <hip/hip_runtime.h>

// MedSAM3D neighborhood compression: out[f,h,w] = sum_n img[f,h,w,n]*W[f,n]
// B=1, F=256, H=W=64, N=25, fp32. 105 MB read + 4.2 MB write.
//
// R6: escalated cache-policy probe on the R3/R5 wave-autonomous structure.
// R5's NT bit (aux=2) gave the only real delta in 4 rounds (21.26->20.56us,
// 5.12->5.31 TB/s). This round: loads aux = NT|SC1 = 18 (strongest
// stream-through hint) + non-temporal float4 store (frees L2 ways for the
// read stream). Unchanged => cache axes exhausted => ROOFLINE.

constexpr int NN    = 25;
constexpr int BLOCK = 256;
constexpr int WAVES = BLOCK / 64;
constexpr int OPW   = 64;          // outputs per wave
constexpr int FPW   = OPW * NN;    // 1600 floats per wave

typedef __attribute__((address_space(3))) void       lds_void;
typedef const __attribute__((address_space(1))) void gbl_void;

__global__ __launch_bounds__(BLOCK) void medsam_compress_kernel(
    const float* __restrict__ img,   // [F*H*W*N]
    const float* __restrict__ W,     // [F*N]
    float* __restrict__ out)         // [F*H*W]
{
    __shared__ float lds[WAVES][FPW];   // 4 x 6400 B = 25,600 B

    const int tid  = threadIdx.x;
    const int w    = tid >> 6;          // wave id in block (uniform)
    const int lane = tid & 63;
    const int gw   = blockIdx.x * WAVES + w;   // global wave id

    const float* gbase = img + (long long)gw * FPW;

    // ---- stage 1600 floats: 6 x (64 lanes x 16B) + 1 x (64 lanes x 4B) ----
    // aux = NT(2) | SC1(16) = 18: non-temporal, stream-through scope hint.
    #pragma unroll
    for (int k = 0; k < 6; ++k) {
        __builtin_amdgcn_global_load_lds(
            (gbl_void*)(gbase + k * 256 + lane * 4),   // per-lane global src
            (lds_void*)&lds[w][k * 256],               // wave-uniform LDS base
            16, 0, 18);
    }
    __builtin_amdgcn_global_load_lds(
        (gbl_void*)(gbase + 1536 + lane),
        (lds_void*)&lds[w][1536],
        4, 0, 18);

    // ---- weights: channel f = gw/64 (wave-uniform) -> scalar loads ----
    const int f = __builtin_amdgcn_readfirstlane(gw >> 6);
    const float* __restrict__ Wf = W + f * NN;
    float wreg[NN];
    #pragma unroll
    for (int n = 0; n < NN; ++n) wreg[n] = Wf[n];

    // ---- wave-scope wait: our 7 staging loads are the only vmcnt ops ----
    asm volatile("s_waitcnt vmcnt(0)" ::: "memory");
    __builtin_amdgcn_sched_barrier(0);

    // ---- dot: 25 ds_read_b32, lane stride 25 (odd) -> conflict-free ----
    const float* row = &lds[w][lane * NN];
    float acc = 0.f;
    #pragma unroll
    for (int n = 0; n < NN; ++n)
        acc += row[n] * wreg[n];

    // ---- coalesced store, non-temporal (zero reuse of output) ----
    __builtin_nontemporal_store(acc, out + (long long)gw * OPW + lane);
}

extern "C" void kernel_launch(void* const* d_in, const int* in_sizes, int n_in,
                              void* d_out, int out_size, void* d_ws, size_t ws_size,
                              hipStream_t stream) {
    const float* img = (const float*)d_in[0];  // (1,256,64,64,25) f32
    const float* W   = (const float*)d_in[1];  // (256,25) f32
    float* out       = (float*)d_out;          // (1,256,64,64) f32

    const int grid = out_size / (OPW * WAVES); // 4096
    medsam_compress_kernel<<<grid, BLOCK, 0, stream>>>(img, W, out);
}